// Round 6
// baseline (89.081 us; speedup 1.0000x reference)
//
#include <hip/hip_runtime.h>
#include <math.h>
#include <stdint.h>

#define CUT   10           // NDCG_CUTOFF
#define N     8192
#define B1    1024
#define HALF  512
#define PERT  (N / HALF)   // 16 items/thread within a group
#define GW    8            // waves per group
#define JPT   (N / B1)     // 8
#define NWAVE (B1 / 64)    // 16

// Sortable key: monotone u32 of float in high bits, ~index low.
// max == max value; value ties break toward SMALLER index (stable argsort(-o)).
__device__ __forceinline__ uint64_t pack_key(float v, int i) {
    uint32_t fb = __float_as_uint(v);
    uint32_t k  = (fb & 0x80000000u) ? ~fb : (fb | 0x80000000u);
    return ((uint64_t)k << 32) | (uint32_t)~(uint32_t)i;
}
__device__ __forceinline__ float key_val(uint64_t key) {
    uint32_t k  = (uint32_t)(key >> 32);
    uint32_t fb = (k & 0x80000000u) ? (k & 0x7FFFFFFFu) : ~k;
    return __uint_as_float(fb);
}
__device__ __forceinline__ int key_idx(uint64_t key) {
    return (int)~(uint32_t)key;
}

// ONE dispatch. Phase A (selection, round-4-validated structure): waves 0-7
// find top-10 of o (stable), waves 8-15 find top-10 of s -> idcg; f32 keys in
// 16 VGPRs/thread, one barrier per pass, lazy winner deselect. Phase B (pair
// sweep, validated rounds 2/4/5, absmax 0.0): delta==0 unless i or j in
// top-10-by-o set T; for unordered pair {i,j} with g_i != g_j:
// bce_ij + bce_ji = 2*softplus(o_lo - o_hi), hi = larger-s member (sign via
// dg = g_i - g_j, exp2 monotone). Pair {top_t, j} counted once: thread j
// counts slot t iff t < pos(j). o-tie pairs masked.
__global__ __launch_bounds__(B1, 4)
void lambdarank_fused(const float* __restrict__ og,
                      const float* __restrict__ sg,
                      float* __restrict__ out)
{
    __shared__ uint64_t wmax[2][2][GW];   // [group][parity][wave-in-group]
    __shared__ float  sh_ov[CUT];
    __shared__ int    sh_oi[CUT];
    __shared__ float  sh_gv[CUT];
    __shared__ float  sh_inv;
    __shared__ double wpart[NWAVE];

    const int tid  = threadIdx.x;
    const int lane = tid & 63;
    const int wid  = tid >> 6;
    const int grp  = tid >> 9;            // 0: o-array, 1: s-array
    const int gtid = tid & (HALF - 1);
    const int gwid = gtid >> 6;

    // ---- Phase A: load my group's array into 16 registers ----
    const float* __restrict__ src = grp ? sg : og;
    float vals[PERT];
    #pragma unroll
    for (int k = 0; k < PERT; ++k) vals[k] = src[gtid + k * HALF];

    float idcg = 0.f;                     // grp-1: redundant-uniform across threads
    int   w_prev = -1;
    for (int t = 0; t < CUT; ++t) {
        // lazy deselect of previous winner (exactly one thread owns the slot)
        #pragma unroll
        for (int k = 0; k < PERT; ++k)
            if (gtid + k * HALF == w_prev) vals[k] = -INFINITY;
        // local argmax; strict > with ascending k keeps smallest own index
        float bv = vals[0]; int bk = 0;
        #pragma unroll
        for (int k = 1; k < PERT; ++k)
            if (vals[k] > bv) { bv = vals[k]; bk = k; }
        uint64_t m = pack_key(bv, gtid + bk * HALF);
        #pragma unroll
        for (int off = 32; off; off >>= 1) {
            uint64_t o = __shfl_xor((unsigned long long)m, off);
            if (o > m) m = o;
        }
        const int par = t & 1;            // parity dbuf: pass t+2's write to this
        if (lane == 0) wmax[grp][par][gwid] = m;   // slot is after barrier t+1
        __syncthreads();
        uint64_t w = wmax[grp][par][0];
        #pragma unroll
        for (int q = 1; q < GW; ++q) { uint64_t v = wmax[grp][par][q]; if (v > w) w = v; }
        const float wv = key_val(w);
        const int   wi = key_idx(w);
        if (grp == 0) {
            if (tid == 0) { sh_ov[t] = wv; sh_oi[t] = wi; }
        } else {
            idcg += (exp2f(wv) - 1.f) / log2f((float)(t + 2));
        }
        w_prev = wi;
    }
    if (tid == HALF) sh_inv = 1.f / idcg;
    __syncthreads();
    if (tid < CUT) sh_gv[tid] = exp2f(sg[sh_oi[tid]]) - 1.f;  // L1-warm reload
    __syncthreads();

    // ---- Phase B: pair sweep (all 1024 threads, 8 j each) ----
    float t_ov[CUT], t_gv[CUT], t_disc[CUT]; int t_oi[CUT];
    #pragma unroll
    for (int t = 0; t < CUT; ++t) {
        t_ov[t]   = sh_ov[t];
        t_gv[t]   = sh_gv[t];
        t_oi[t]   = sh_oi[t];
        t_disc[t] = 1.f / log2f((float)(t + 2));
    }
    const float inv_idcg = sh_inv;

    double acc = 0.0;
    #pragma unroll 1                      // keep body small; TLP hides L1/L2 loads
    for (int k = 0; k < JPT; ++k) {
        const int j  = tid + k * B1;
        const float oj = og[j];
        const float gj = exp2f(sg[j]) - 1.f;
        int pos = CUT; float discj = 0.f; // static-indexed pick, no scratch
        #pragma unroll
        for (int t = 0; t < CUT; ++t)
            if (t_oi[t] == j) { pos = t; discj = t_disc[t]; }
        #pragma unroll
        for (int t = 0; t < CUT; ++t) {
            const float oi = t_ov[t];
            const float dg = t_gv[t] - gj;          // sign(dg) == sign(s_i - s_j)
            const float dd = t_disc[t] - discj;
            const float delta = fabsf(dg * dd) * inv_idcg;
            const float darg  = copysignf(1.f, dg) * (oj - oi);   // o_lo - o_hi
            const float e  = exp2f(-fabsf(darg) * 1.4426950408889634f);
            const float l  = log2f(1.f + e);
            const float sp = fmaxf(darg, 0.f) + l * 0.6931471805599453f;
            if (t < pos && oi != oj)
                acc += (double)(delta * (2.f * sp));
        }
    }

    // ---- deterministic block reduce ----
    #pragma unroll
    for (int off = 32; off; off >>= 1) acc += __shfl_down(acc, off);
    if (lane == 0) wpart[wid] = acc;
    __syncthreads();
    if (tid == 0) {
        double tot = 0.0;
        #pragma unroll
        for (int w = 0; w < NWAVE; ++w) tot += wpart[w];
        out[0] = (float)(tot / (double)N);
    }
}

extern "C" void kernel_launch(void* const* d_in, const int* in_sizes, int n_in,
                              void* d_out, int out_size, void* d_ws, size_t ws_size,
                              hipStream_t stream) {
    const float* o = (const float*)d_in[0];
    const float* s = (const float*)d_in[1];
    float* out = (float*)d_out;
    lambdarank_fused<<<dim3(1), dim3(B1), 0, stream>>>(o, s, out);
}

// Round 14
// 70.687 us; speedup vs baseline: 1.2602x; 1.2602x over previous
//
#include <hip/hip_runtime.h>
#include <math.h>
#include <stdint.h>

#define CUT  10          // NDCG_CUTOFF
#define N    8192

// ---- ws layout (bytes) ----
//  [0,256)    double partials[32]
//  [256,296)  float  top_ov[10]
//  [296,336)  float  top_gv[10]
//  [336,340)  float  inv_idcg
//  [344,384)  int    top_oi[10]
//  [512,3072) u64    cand[320]  (o:160, s:160)
#define WS_PART(ws) ((double*)(ws))
#define WS_OV(ws)   ((float*)((char*)(ws) + 256))
#define WS_GV(ws)   ((float*)((char*)(ws) + 296))
#define WS_INV(ws)  ((float*)((char*)(ws) + 336))
#define WS_OI(ws)   ((int*)((char*)(ws) + 344))
#define WS_CAND(ws) ((uint64_t*)((char*)(ws) + 512))

// Sortable key: monotone u32 of float in high bits, ~index low.
// max == max value; value ties break toward SMALLER index (stable argsort(-o)).
__device__ __forceinline__ uint64_t pack_key(float v, int i) {
    uint32_t fb = __float_as_uint(v);
    uint32_t k  = (fb & 0x80000000u) ? ~fb : (fb | 0x80000000u);
    return ((uint64_t)k << 32) | (uint32_t)~(uint32_t)i;
}
__device__ __forceinline__ float key_val(uint64_t key) {
    uint32_t k  = (uint32_t)(key >> 32);
    uint32_t fb = (k & 0x80000000u) ? (k & 0x7FFFFFFFu) : ~k;
    return __uint_as_float(fb);
}
__device__ __forceinline__ int key_idx(uint64_t key) {
    return (int)~(uint32_t)key;
}

// ========== K1: chunk-local top-10 candidates (32 blocks x 64, no barriers) ==========
// Blocks 0-15: o-chunks of 512; blocks 16-31: s-chunks. 8 items/thread in regs;
// 10 masked-argmax passes (t-loop NOT unrolled — ICE avoidance; matches the
// round-3 code shape that compiled), each a 6-level u64 shfl-max chain.
// Keys unique (index in low bits) so deselect-by-equality is exact.
__global__ __launch_bounds__(64)
void k_cand(const float* __restrict__ og, const float* __restrict__ sg,
            void* __restrict__ ws)
{
    const int lane = threadIdx.x;
    const int b    = blockIdx.x;
    const int grp  = b >> 4;          // 0: o, 1: s
    const int cb   = b & 15;
    const float* __restrict__ src = grp ? sg : og;
    const int base = cb * 512;

    uint64_t reg[8];
    #pragma unroll
    for (int k = 0; k < 8; ++k) {
        const int i = base + lane + 64 * k;   // coalesced
        reg[k] = pack_key(src[i], i);
    }
    uint64_t* __restrict__ outc = WS_CAND(ws) + grp * 160 + cb * CUT;

    for (int t = 0; t < CUT; ++t) {           // no pragma: keep body un-duplicated
        uint64_t m = reg[0];
        #pragma unroll
        for (int k = 1; k < 8; ++k) if (reg[k] > m) m = reg[k];
        #pragma unroll
        for (int off = 32; off; off >>= 1) {
            uint64_t o = __shfl_xor((unsigned long long)m, off);
            if (o > m) m = o;
        }
        if (lane == 0) outc[t] = m;
        #pragma unroll
        for (int k = 0; k < 8; ++k) if (reg[k] == m) reg[k] = 0;
    }
}

// ========== K2: merge candidates (1 block x 128; 2 independent waves) ==========
// Wave 0: merge 160 o-cands -> stable top-10 (full keys => global stable
// order) written directly from lane 0; gains after. Wave 1: 160 s-cands ->
// idcg -> inv. Scalar c0/c1/c2 (no register arrays), t-loop not unrolled.
__global__ __launch_bounds__(128)
void k_merge(const float* __restrict__ sg, void* __restrict__ ws)
{
    const int tid  = threadIdx.x;
    const int lane = tid & 63;
    const int wv   = tid >> 6;
    const uint64_t* __restrict__ cand = WS_CAND(ws) + wv * 160;

    uint64_t c0 = cand[lane];
    uint64_t c1 = cand[64 + lane];
    uint64_t c2 = (lane < 32) ? cand[128 + lane] : 0;  // 0 = -inf sentinel

    float idcg = 0.f;                          // used by wave 1 only
    for (int t = 0; t < CUT; ++t) {            // no pragma
        uint64_t m = c0;
        if (c1 > m) m = c1;
        if (c2 > m) m = c2;
        #pragma unroll
        for (int off = 32; off; off >>= 1) {
            uint64_t o = __shfl_xor((unsigned long long)m, off);
            if (o > m) m = o;
        }
        if (wv == 0) {
            if (lane == 0) { WS_OV(ws)[t] = key_val(m); WS_OI(ws)[t] = key_idx(m); }
        } else {
            idcg += (exp2f(key_val(m)) - 1.f) / log2f((float)(t + 2));
        }
        if (c0 == m) c0 = 0;
        if (c1 == m) c1 = 0;
        if (c2 == m) c2 = 0;
    }
    if (wv == 0 && lane == 0) {
        for (int t = 0; t < CUT; ++t)          // same-thread reread of WS_OI: ordered
            WS_GV(ws)[t] = exp2f(sg[WS_OI(ws)[t]]) - 1.f;
    }
    if (wv == 1 && lane == 0) WS_INV(ws)[0] = 1.f / idcg;
}

// ========== K3: pair sweep (32 blocks x 256) — verbatim round-5-proven ==========
// delta==0 unless i or j in top-10-by-o set T; for unordered pair {i,j} with
// g_i != g_j: bce_ij + bce_ji = 2*softplus(o_lo - o_hi), hi = larger-s member
// (sign via dg = g_i - g_j, exp2 monotone). Pair {top_t, j} counted once:
// thread j counts slot t iff t < pos(j). o-tie pairs masked.
#define B2 256
#define G2 (N / B2)   // 32

__global__ __launch_bounds__(B2)
void k_sweep(const float* __restrict__ og, const float* __restrict__ sg,
             void* __restrict__ ws)
{
    __shared__ double wpart[B2 / 64];
    const int tid = threadIdx.x;
    const int j   = blockIdx.x * B2 + tid;

    float t_ov[CUT], t_gv[CUT], t_disc[CUT]; int t_oi[CUT];
    #pragma unroll
    for (int t = 0; t < CUT; ++t) {
        t_ov[t]   = WS_OV(ws)[t];
        t_gv[t]   = WS_GV(ws)[t];
        t_oi[t]   = WS_OI(ws)[t];
        t_disc[t] = 1.f / log2f((float)(t + 2));
    }
    const float inv_idcg = WS_INV(ws)[0];

    const float oj = og[j];
    const float gj = exp2f(sg[j]) - 1.f;
    int pos = CUT; float discj = 0.f;
    #pragma unroll
    for (int t = 0; t < CUT; ++t)
        if (t_oi[t] == j) { pos = t; discj = t_disc[t]; }

    double acc = 0.0;
    #pragma unroll
    for (int t = 0; t < CUT; ++t) {
        const float oi = t_ov[t];
        const float dg = t_gv[t] - gj;           // sign(dg) == sign(s_i - s_j)
        const float dd = t_disc[t] - discj;
        const float delta = fabsf(dg * dd) * inv_idcg;
        const float darg  = copysignf(1.f, dg) * (oj - oi);   // o_lo - o_hi
        const float e  = exp2f(-fabsf(darg) * 1.4426950408889634f);
        const float l  = log2f(1.f + e);
        const float sp = fmaxf(darg, 0.f) + l * 0.6931471805599453f;
        if (t < pos && oi != oj)
            acc += (double)(delta * (2.f * sp));
    }
    #pragma unroll
    for (int off = 32; off; off >>= 1) acc += __shfl_down(acc, off);
    const int lane = tid & 63, wid = tid >> 6;
    if (lane == 0) wpart[wid] = acc;
    __syncthreads();
    if (tid == 0) {
        double tot = 0.0;
        #pragma unroll
        for (int w = 0; w < B2 / 64; ++w) tot += wpart[w];
        WS_PART(ws)[blockIdx.x] = tot;
    }
}

// ========== K4: deterministic final sum — verbatim round-5-proven ==========
__global__ __launch_bounds__(64)
void k_final(void* __restrict__ ws, float* __restrict__ out)
{
    const int lane = threadIdx.x;
    double v = (lane < G2) ? WS_PART(ws)[lane] : 0.0;
    #pragma unroll
    for (int off = 32; off; off >>= 1) v += __shfl_down(v, off);
    if (lane == 0) out[0] = (float)(v / (double)N);
}

extern "C" void kernel_launch(void* const* d_in, const int* in_sizes, int n_in,
                              void* d_out, int out_size, void* d_ws, size_t ws_size,
                              hipStream_t stream) {
    const float* o = (const float*)d_in[0];
    const float* s = (const float*)d_in[1];
    float* out = (float*)d_out;
    k_cand <<<dim3(32), dim3(64),  0, stream>>>(o, s, d_ws);
    k_merge<<<dim3(1),  dim3(128), 0, stream>>>(s, d_ws);
    k_sweep<<<dim3(G2), dim3(B2),  0, stream>>>(o, s, d_ws);
    k_final<<<dim3(1),  dim3(64),  0, stream>>>(d_ws, out);
}

// Round 18
// 67.563 us; speedup vs baseline: 1.3185x; 1.0462x over previous
//
#include <hip/hip_runtime.h>
#include <math.h>
#include <stdint.h>

#define CUT 10           // NDCG_CUTOFF
#define N   8192
#define NB  32           // blocks
#define BT  256          // threads/block

#define CFLAG_MAGIC 0x13579BDFu   // != 0xAAAAAAAA poison
#define PFLAG_MAGIC 0x2468ACE1u

// ws layout (bytes):
//  [0,256)    u64 partial_bits[32]
//  [256,384)  u32 cflag[32]
//  [384,512)  u32 pflag[32]
//  [512,3072) u64 cand[320]  (o:0-159, s:160-319)
#define WS_PART(ws)  ((uint64_t*)(ws))
#define WS_CFLAG(ws) ((uint32_t*)((char*)(ws) + 256))
#define WS_PFLAG(ws) ((uint32_t*)((char*)(ws) + 384))
#define WS_CAND(ws)  ((uint64_t*)((char*)(ws) + 512))

// Sortable key: monotone u32 of float in high bits, ~index low.
// max == max value; value ties break toward SMALLER index (stable argsort(-o)).
__device__ __forceinline__ uint64_t pack_key(float v, int i) {
    uint32_t fb = __float_as_uint(v);
    uint32_t k  = (fb & 0x80000000u) ? ~fb : (fb | 0x80000000u);
    return ((uint64_t)k << 32) | (uint32_t)~(uint32_t)i;
}
__device__ __forceinline__ float key_val(uint64_t key) {
    uint32_t k  = (uint32_t)(key >> 32);
    uint32_t fb = (k & 0x80000000u) ? (k & 0x7FFFFFFFu) : ~k;
    return __uint_as_float(fb);
}
__device__ __forceinline__ int key_idx(uint64_t key) {
    return (int)~(uint32_t)key;
}

// ONE dispatch, 32 co-resident blocks (<= 256 CUs; each block posts its flag
// BEFORE spinning, so even partial residency cannot deadlock the DAG).
// Cross-block visibility per G16: release/acquire agent-scope atomics only.
// Phase A: wave 0 of block b computes chunk-local top-10 candidates
//          (blocks 0-15: o-chunks of 512; 16-31: s-chunks) -> cand[] + cflag.
// Phase B: gate on all 32 cflags; EVERY block redundantly merges 320 cands
//          (wave 0: o -> tops; wave 1: s -> idcg) into LDS. No 2nd gate.
// Phase C: sweep 1 item/thread (validated algebra, absmax 0.0 x4):
//          delta==0 unless i or j in top-10-by-o set T; for unordered {i,j}
//          with g_i != g_j: bce_ij+bce_ji = 2*softplus(o_lo - o_hi), hi =
//          larger-s member (sign via dg, exp2 monotone); slot t counted by
//          thread j iff t < pos(j); o-tie pairs masked.
// Phase D: block 0 gates on 32 pflags, fixed-order final sum -> out.
__global__ __launch_bounds__(BT)
void lambdarank_one(const float* __restrict__ og, const float* __restrict__ sg,
                    float* __restrict__ out, void* __restrict__ ws)
{
    uint64_t* part  = WS_PART(ws);
    uint32_t* cflag = WS_CFLAG(ws);
    uint32_t* pflag = WS_PFLAG(ws);
    uint64_t* cand  = WS_CAND(ws);

    const int tid  = threadIdx.x;
    const int lane = tid & 63;
    const int wv   = tid >> 6;
    const int b    = blockIdx.x;

    __shared__ float  sh_ov[CUT];
    __shared__ int    sh_oi[CUT];
    __shared__ float  sh_gv[CUT];
    __shared__ float  sh_inv;
    __shared__ double wpart[BT / 64];

    // ---------- Phase A: chunk candidates (wave 0 only) ----------
    if (wv == 0) {
        const int grp  = b >> 4;          // 0: o, 1: s
        const int cb   = b & 15;
        const float* __restrict__ src = grp ? sg : og;
        const int base = cb * 512;
        uint64_t reg[8];
        #pragma unroll
        for (int k = 0; k < 8; ++k) {
            const int i = base + lane + 64 * k;   // coalesced
            reg[k] = pack_key(src[i], i);
        }
        uint64_t* __restrict__ outc = cand + grp * 160 + cb * CUT;
        for (int t = 0; t < CUT; ++t) {           // no pragma (ICE avoidance)
            uint64_t m = reg[0];
            #pragma unroll
            for (int k = 1; k < 8; ++k) if (reg[k] > m) m = reg[k];
            #pragma unroll
            for (int off = 32; off; off >>= 1) {
                uint64_t o = __shfl_xor((unsigned long long)m, off);
                if (o > m) m = o;
            }
            if (lane == 0)
                __hip_atomic_store(&outc[t], m, __ATOMIC_RELAXED, __HIP_MEMORY_SCOPE_AGENT);
            #pragma unroll
            for (int k = 0; k < 8; ++k) if (reg[k] == m) reg[k] = 0;
        }
        if (lane == 0)
            __hip_atomic_store(&cflag[b], CFLAG_MAGIC, __ATOMIC_RELEASE, __HIP_MEMORY_SCOPE_AGENT);
    }

    // ---------- gate: all candidates visible ----------
    if (tid < NB)
        while (__hip_atomic_load(&cflag[tid], __ATOMIC_ACQUIRE, __HIP_MEMORY_SCOPE_AGENT)
               != CFLAG_MAGIC) {}
    __syncthreads();

    // ---------- Phase B: redundant per-block merge (waves 0,1) ----------
    if (wv < 2) {
        const uint64_t* __restrict__ c = cand + wv * 160;
        uint64_t c0 = __hip_atomic_load(&c[lane],      __ATOMIC_RELAXED, __HIP_MEMORY_SCOPE_AGENT);
        uint64_t c1 = __hip_atomic_load(&c[64 + lane], __ATOMIC_RELAXED, __HIP_MEMORY_SCOPE_AGENT);
        uint64_t c2 = (lane < 32)
            ? __hip_atomic_load(&c[128 + lane], __ATOMIC_RELAXED, __HIP_MEMORY_SCOPE_AGENT) : 0;
        float idcg = 0.f;                          // wave 1 only
        for (int t = 0; t < CUT; ++t) {            // no pragma
            uint64_t m = c0;
            if (c1 > m) m = c1;
            if (c2 > m) m = c2;
            #pragma unroll
            for (int off = 32; off; off >>= 1) {
                uint64_t o = __shfl_xor((unsigned long long)m, off);
                if (o > m) m = o;
            }
            if (wv == 0) {
                if (lane == 0) { sh_ov[t] = key_val(m); sh_oi[t] = key_idx(m); }
            } else {
                idcg += (exp2f(key_val(m)) - 1.f) / log2f((float)(t + 2));
            }
            if (c0 == m) c0 = 0;
            if (c1 == m) c1 = 0;
            if (c2 == m) c2 = 0;
        }
        if (wv == 0 && lane == 0) {
            for (int t = 0; t < CUT; ++t)          // input array: always coherent
                sh_gv[t] = exp2f(sg[sh_oi[t]]) - 1.f;
        }
        if (wv == 1 && lane == 0) sh_inv = 1.f / idcg;
    }
    __syncthreads();

    // ---------- Phase C: pair sweep, 1 item/thread ----------
    float t_ov[CUT], t_gv[CUT], t_disc[CUT]; int t_oi[CUT];
    #pragma unroll
    for (int t = 0; t < CUT; ++t) {
        t_ov[t]   = sh_ov[t];
        t_gv[t]   = sh_gv[t];
        t_oi[t]   = sh_oi[t];
        t_disc[t] = 1.f / log2f((float)(t + 2));
    }
    const float inv_idcg = sh_inv;
    const int   j  = b * BT + tid;
    const float oj = og[j];
    const float gj = exp2f(sg[j]) - 1.f;
    int pos = CUT; float discj = 0.f;
    #pragma unroll
    for (int t = 0; t < CUT; ++t)
        if (t_oi[t] == j) { pos = t; discj = t_disc[t]; }

    double acc = 0.0;
    #pragma unroll
    for (int t = 0; t < CUT; ++t) {
        const float oi = t_ov[t];
        const float dg = t_gv[t] - gj;           // sign(dg) == sign(s_i - s_j)
        const float dd = t_disc[t] - discj;
        const float delta = fabsf(dg * dd) * inv_idcg;
        const float darg  = copysignf(1.f, dg) * (oj - oi);   // o_lo - o_hi
        const float e  = exp2f(-fabsf(darg) * 1.4426950408889634f);
        const float l  = log2f(1.f + e);
        const float sp = fmaxf(darg, 0.f) + l * 0.6931471805599453f;
        if (t < pos && oi != oj)
            acc += (double)(delta * (2.f * sp));
    }
    #pragma unroll
    for (int off = 32; off; off >>= 1) acc += __shfl_down(acc, off);
    if (lane == 0) wpart[wv] = acc;
    __syncthreads();
    if (tid == 0) {
        double tot = 0.0;
        #pragma unroll
        for (int w = 0; w < BT / 64; ++w) tot += wpart[w];
        __hip_atomic_store(&part[b], (uint64_t)__double_as_longlong(tot),
                           __ATOMIC_RELAXED, __HIP_MEMORY_SCOPE_AGENT);
        __hip_atomic_store(&pflag[b], PFLAG_MAGIC, __ATOMIC_RELEASE, __HIP_MEMORY_SCOPE_AGENT);
    }

    // ---------- Phase D: block 0 deterministic final sum ----------
    if (b == 0) {
        if (tid < NB)
            while (__hip_atomic_load(&pflag[tid], __ATOMIC_ACQUIRE, __HIP_MEMORY_SCOPE_AGENT)
                   != PFLAG_MAGIC) {}
        __syncthreads();
        if (wv == 0) {
            double v = (lane < NB)
                ? __longlong_as_double((long long)__hip_atomic_load(
                      &part[lane], __ATOMIC_RELAXED, __HIP_MEMORY_SCOPE_AGENT))
                : 0.0;
            #pragma unroll
            for (int off = 32; off; off >>= 1) v += __shfl_down(v, off);
            if (lane == 0) out[0] = (float)(v / (double)N);
        }
    }
}

extern "C" void kernel_launch(void* const* d_in, const int* in_sizes, int n_in,
                              void* d_out, int out_size, void* d_ws, size_t ws_size,
                              hipStream_t stream) {
    const float* o = (const float*)d_in[0];
    const float* s = (const float*)d_in[1];
    float* out = (float*)d_out;
    lambdarank_one<<<dim3(NB), dim3(BT), 0, stream>>>(o, s, out, d_ws);
}